// Round 10
// baseline (498.442 us; speedup 1.0000x reference)
//
#include <hip/hip_runtime.h>
#include <cstdint>
#include <cstddef>

#define DF 128
#define NL 5
#define NB 1024
#define BN_EPS 1e-5f

typedef short bf16x8 __attribute__((ext_vector_type(8)));
typedef float f32x4 __attribute__((ext_vector_type(4)));

typedef __attribute__((address_space(3))) uint32_t lds_u32;
typedef __attribute__((address_space(1))) uint32_t glb_u32;

__device__ __forceinline__ void gload16(const void* g, void* l) {
#if __has_builtin(__builtin_amdgcn_global_load_lds)
  __builtin_amdgcn_global_load_lds((const glb_u32*)g, (lds_u32*)l, 16, 0, 0);
#else
  *(uint4*)l = *(const uint4*)g;
#endif
}

// fp32 -> bf16 (RNE)
__device__ __forceinline__ ushort f2b(float f) {
  union { float f; uint32_t u; } v; v.f = f;
  uint32_t u = v.u + 0x7fffu + ((v.u >> 16) & 1u);
  return (ushort)(u >> 16);
}
__device__ __forceinline__ uint32_t pk2(float a, float b) {
  return (uint32_t)f2b(a) | ((uint32_t)f2b(b) << 16);
}
// signed int8 from byte `sh` of w, as float
__device__ __forceinline__ float i8f(uint32_t w, int sh) {
  return (float)(int8_t)((w >> sh) & 0xffu);
}

// ---------------- precompute ----------------

__global__ void k_deg2(const int* __restrict__ row, const int* __restrict__ col,
                       int* __restrict__ degi, int* __restrict__ indeg, int E) {
  int i = blockIdx.x * blockDim.x + threadIdx.x;
  if (i < E) {
    atomicAdd(&degi[row[i]], 1);
    atomicAdd(&indeg[col[i]], 1);
  }
}

// dinv + in-degree histogram (two-level: LDS histogram, one global add per bin/block)
__global__ void k_dinvhist(const int* __restrict__ degi, const int* __restrict__ indeg,
                           float* __restrict__ dinv, int* __restrict__ hist, int N) {
  __shared__ int lh[NB];
  for (int j = threadIdx.x; j < NB; j += blockDim.x) lh[j] = 0;
  __syncthreads();
  int i = blockIdx.x * blockDim.x + threadIdx.x;
  if (i < N) {
    dinv[i] = 1.0f / sqrtf((float)(degi[i] + 1));
    atomicAdd(&lh[min(indeg[i], NB - 1)], 1);
  }
  __syncthreads();
  for (int j = threadIdx.x; j < NB; j += blockDim.x) {
    int c = lh[j];
    if (c) atomicAdd(&hist[j], c);
  }
}

// exclusive scans of hist (node starts) and hist*d (edge starts); one block of NB.
__global__ void k_scan(const int* __restrict__ hist,
                       int* __restrict__ nodeStart, int* __restrict__ edgeStart) {
  __shared__ int2 sm[NB];
  int t = threadIdx.x;
  int c = hist[t];
  int2 v; v.x = c; v.y = c * t;
  sm[t] = v;
  __syncthreads();
  for (int off = 1; off < NB; off <<= 1) {
    int2 add; add.x = 0; add.y = 0;
    if (t >= off) add = sm[t - off];
    __syncthreads();
    sm[t].x += add.x; sm[t].y += add.y;
    __syncthreads();
  }
  nodeStart[t] = sm[t].x - c;        // exclusive
  edgeStart[t] = sm[t].y - c * t;
}

// assign permuted slots (two-level rank: LDS local rank + per-block bin base claim)
__global__ void k_assign(const int* __restrict__ indeg, const float* __restrict__ dinv,
                         const int* __restrict__ nodeStart, const int* __restrict__ edgeStart,
                         int* __restrict__ binCursor,
                         int* __restrict__ perm, int* __restrict__ invperm,
                         int* __restrict__ startP, int* __restrict__ cursorP,
                         int* __restrict__ degP, float* __restrict__ dinvP, int N) {
  __shared__ int lh[NB];
  __shared__ int gbase[NB];
  for (int j = threadIdx.x; j < NB; j += blockDim.x) lh[j] = 0;
  __syncthreads();
  int nd = blockIdx.x * blockDim.x + threadIdx.x;
  bool valid = nd < N;
  int d = 0, bin = 0, lrank = 0;
  if (valid) {
    d = indeg[nd];
    bin = min(d, NB - 1);
    lrank = atomicAdd(&lh[bin], 1);
  }
  __syncthreads();
  for (int j = threadIdx.x; j < NB; j += blockDim.x) {
    int c = lh[j];
    gbase[j] = c ? atomicAdd(&binCursor[j], c) : 0;
  }
  __syncthreads();
  if (!valid) return;
  int r = gbase[bin] + lrank;
  int i = nodeStart[bin] + r;
  perm[i] = nd;
  invperm[nd] = i;
  int st = edgeStart[bin] + r * d;
  startP[i] = st;
  cursorP[i] = st;
  degP[i] = d;
  dinvP[i] = dinv[nd];
}

// bucket-scatter edges into permuted CSR (+ pack attrs, 2b each, dst-sorted).
// pairS[pos] = {src (permuted), nrm bits} — one 8B load in the gather.
__global__ void k_fillpack(const int* __restrict__ row, const int* __restrict__ col,
                           const float* __restrict__ dinv, const int* __restrict__ invperm,
                           int* __restrict__ cursorP, int2* __restrict__ pairS,
                           const int* __restrict__ ea, uint32_t* __restrict__ epS, int E) {
  int tid = blockIdx.x * blockDim.x + threadIdx.x;
  int e = tid >> 3, t = tid & 7;
  if (e >= E) return;
  int pos;
  if (t == 0) {
    int r = row[e], c = col[e];
    pos = atomicAdd(&cursorP[invperm[c]], 1);
    int2 pv; pv.x = invperm[r];
    float nr = dinv[r] * dinv[c];
    pv.y = __float_as_int(nr);
    pairS[pos] = pv;
  }
  pos = __shfl(pos, 0, 8);
  const int4* p = ((const int4*)ea) + (size_t)e * 32 + t * 4;
  uint32_t w = 0;
  #pragma unroll
  for (int q = 0; q < 4; ++q) {
    int4 a = p[q];
    w |= ((uint32_t)(a.x & 3)) << (8 * q);
    w |= ((uint32_t)(a.y & 3)) << (8 * q + 2);
    w |= ((uint32_t)(a.z & 3)) << (8 * q + 4);
    w |= ((uint32_t)(a.w & 3)) << (8 * q + 6);
  }
  epS[(size_t)pos * 8 + t] = w;
}

// BN affine fold + W fp32->bf16
__global__ void k_params(const float* __restrict__ g, const float* __restrict__ be,
                         const float* __restrict__ mn, const float* __restrict__ vr,
                         float* __restrict__ s, float* __restrict__ t,
                         const float* __restrict__ W, ushort* __restrict__ Wb,
                         int nbn, int nw) {
  int i = blockIdx.x * blockDim.x + threadIdx.x;
  if (i < nw) Wb[i] = f2b(W[i]);
  if (i < nbn) {
    float sc = g[i] / sqrtf(vr[i] + BN_EPS);
    s[i] = sc;
    t[i] = be[i] - mn[i] * sc;
  }
}

// ---------------- MFMA GEMM: hl(int8 + per-row scale) = in @ W^T + b ----------------
template <typename IT>
__global__ __launch_bounds__(256) void k_gemm(
    const IT* __restrict__ in, const int* __restrict__ perm,
    const ushort* __restrict__ Wb, const float* __restrict__ bl,
    uint8_t* __restrict__ hl, float* __restrict__ scale, int N)
{
  __shared__ uint4 lA[128 * 16];
  __shared__ uint4 lW[128 * 16];
  const int t = threadIdx.x;
  const int row0 = blockIdx.x * 128;
  const int wv = t >> 6;
  const int l  = t & 63;

  #pragma unroll
  for (int it = 0; it < 8; ++it) {
    int ubase = (it * 4 + wv) * 64;
    int lin = ubase + l;
    int r = lin >> 4, u = lin & 15;
    gload16((const void*)((const uint4*)Wb + (r << 4) + (u ^ (r & 7))), (void*)(lW + ubase));
  }

  if constexpr (sizeof(IT) == 2) {
    #pragma unroll
    for (int it = 0; it < 8; ++it) {
      int ubase = (it * 4 + wv) * 64;
      int lin = ubase + l;
      int r = lin >> 4, u = lin & 15;
      int gn = row0 + r;
      int gnc = gn < N ? gn : N - 1;     // clamp: garbage rows discarded
      gload16((const void*)((const uint4*)in + (size_t)gnc * 16 + (u ^ (r & 7))),
              (void*)(lA + ubase));
    }
  } else {
    #pragma unroll
    for (int it = 0; it < 8; ++it) {
      int lin = it * 256 + t;
      int r = lin >> 4, u = lin & 15;
      int gn = row0 + r;
      uint4 pk = make_uint4(0u, 0u, 0u, 0u);
      if (gn < N) {
        int src = perm[gn];
        const float4* p = (const float4*)((const float*)in + (size_t)src * DF + u * 8);
        float4 f0 = p[0], f1 = p[1];
        pk.x = pk2(f0.x, f0.y); pk.y = pk2(f0.z, f0.w);
        pk.z = pk2(f1.x, f1.y); pk.w = pk2(f1.z, f1.w);
      }
      lA[(r << 4) | (u ^ (r & 7))] = pk;
    }
  }
  __syncthreads();

  const int lr = l & 15;
  const int lk = l >> 4;

  f32x4 acc[2][8];
  #pragma unroll
  for (int rt = 0; rt < 2; ++rt)
    #pragma unroll
    for (int ct = 0; ct < 8; ++ct) acc[rt][ct] = (f32x4){0.f, 0.f, 0.f, 0.f};

  #pragma unroll
  for (int ks = 0; ks < 4; ++ks) {
    const int kofs = ks * 4 + lk;
    bf16x8 af[2], wf[8];
    #pragma unroll
    for (int rt = 0; rt < 2; ++rt) {
      int r = wv * 32 + rt * 16 + lr;
      af[rt] = *reinterpret_cast<const bf16x8*>(&lA[(r << 4) | (kofs ^ (r & 7))]);
    }
    #pragma unroll
    for (int ct = 0; ct < 8; ++ct) {
      int r = ct * 16 + lr;
      wf[ct] = *reinterpret_cast<const bf16x8*>(&lW[(r << 4) | (kofs ^ (r & 7))]);
    }
    #pragma unroll
    for (int rt = 0; rt < 2; ++rt)
      #pragma unroll
      for (int ct = 0; ct < 8; ++ct)
        acc[rt][ct] = __builtin_amdgcn_mfma_f32_16x16x32_bf16(af[rt], wf[ct], acc[rt][ct], 0, 0, 0);
  }

  float bb[8];
  #pragma unroll
  for (int ct = 0; ct < 8; ++ct) bb[ct] = bl[ct * 16 + lr];

  __syncthreads();                       // all waves done reading lA/lW
  uint8_t* q8 = (uint8_t*)lA;            // 16 KiB transpose buffer

  #pragma unroll
  for (int rt = 0; rt < 2; ++rt) {
    #pragma unroll
    for (int rg = 0; rg < 4; ++rg) {
      int rloc = wv * 32 + rt * 16 + lk * 4 + rg;
      float o[8];
      float am = 0.f;
      #pragma unroll
      for (int ct = 0; ct < 8; ++ct) {
        o[ct] = acc[rt][ct][rg] + bb[ct];
        am = fmaxf(am, fabsf(o[ct]));
      }
      am = fmaxf(am, __shfl_xor(am, 1));
      am = fmaxf(am, __shfl_xor(am, 2));
      am = fmaxf(am, __shfl_xor(am, 4));
      am = fmaxf(am, __shfl_xor(am, 8));
      float inv = am > 0.f ? 127.f / am : 0.f;
      int gn = row0 + rloc;
      if (lr == 0 && gn < N) scale[gn] = am * (1.f / 127.f);
      #pragma unroll
      for (int ct = 0; ct < 8; ++ct) {
        int q = __float2int_rn(o[ct] * inv);
        q8[rloc * DF + ct * 16 + lr] = (uint8_t)(q & 0xff);
      }
    }
  }
  __syncthreads();

  // coalesced store: 128 rows x 128 B, 8 B chunks
  #pragma unroll
  for (int it = 0; it < 8; ++it) {
    int chunk = it * 256 + t;            // 0..2047
    int rloc = chunk >> 4;
    int gn = row0 + rloc;
    if (gn < N) {
      uint2 v = *(const uint2*)(q8 + chunk * 8);
      *(uint2*)(hl + (size_t)gn * DF + (chunk & 15) * 8) = v;
    }
  }
}

// ---------------- segmented gather-reduce (permuted space, int8 hl) ----------------
// 8 dest rows per wave (degree-uniform), 8 lanes/row, 16 feats/lane.
// Chunk-of-8 software pipeline: ISSUE all loads (up to 24 VMEM in flight),
// then COMPUTE — amortizes the ~600cy L3 latency of the random hl reads.
#define ISSUE(K)                                              \
  if (K < m) {                                                \
    int src = __shfl(pv.x, K, 8);                             \
    hw##K = hl4[(size_t)src * 8 + s8];                        \
    pw##K = epS[(size_t)(base + c0 + K) * 8 + s8];            \
    sc##K = scaleArr[src];                                    \
  }

#define ACC4(HW, PW, NR, SC, J0)                                                          \
  a[J0+0] += NR * fmaxf(fmaf(i8f(HW, 0),  SC, (float)((PW >> (2*(J0)+0)) & 3u)), 0.f);    \
  a[J0+1] += NR * fmaxf(fmaf(i8f(HW, 8),  SC, (float)((PW >> (2*(J0)+2)) & 3u)), 0.f);    \
  a[J0+2] += NR * fmaxf(fmaf(i8f(HW, 16), SC, (float)((PW >> (2*(J0)+4)) & 3u)), 0.f);    \
  a[J0+3] += NR * fmaxf(fmaf(i8f(HW, 24), SC, (float)((PW >> (2*(J0)+6)) & 3u)), 0.f);

#define CONSUME(K)                                            \
  if (K < m) {                                                \
    float nr = __int_as_float(__shfl(pv.y, K, 8));            \
    ACC4(hw##K.x, pw##K, nr, sc##K, 0)                        \
    ACC4(hw##K.y, pw##K, nr, sc##K, 4)                        \
    ACC4(hw##K.z, pw##K, nr, sc##K, 8)                        \
    ACC4(hw##K.w, pw##K, nr, sc##K, 12)                       \
  }

template <typename AT, bool LAST>
__global__ __launch_bounds__(256) void k_gather(
    const int* __restrict__ startP, const int* __restrict__ degP,
    const float* __restrict__ dinvP,
    const int2* __restrict__ pairS,
    const uint32_t* __restrict__ epS,
    const uint4* __restrict__ hl4, const float* __restrict__ scaleArr,
    const float* __restrict__ rootl, const float* __restrict__ sl,
    const float* __restrict__ tl, const int* __restrict__ perm,
    AT* __restrict__ acc, int N)
{
  int gw = (blockIdx.x * blockDim.x + threadIdx.x) >> 6;
  int lane = threadIdx.x & 63;
  int s8 = lane & 7;
  int i = gw * 8 + (lane >> 3);
  if (i >= N) return;
  int base = startP[i], n = degP[i];
  float di = dinvP[i];
  float invdeg = di * di;

  float a[16];
  #pragma unroll
  for (int j = 0; j < 16; ++j) a[j] = 0.f;

  for (int c0 = 0; c0 < n; c0 += 8) {
    const int m = min(8, n - c0);          // group-uniform (degree-binned)
    int2 pv = (s8 < m) ? pairS[base + c0 + s8] : make_int2(0, 0);
    uint4 hw0, hw1, hw2, hw3, hw4, hw5, hw6, hw7;
    uint32_t pw0, pw1, pw2, pw3, pw4, pw5, pw6, pw7;
    float sc0, sc1, sc2, sc3, sc4, sc5, sc6, sc7;
    ISSUE(0) ISSUE(1) ISSUE(2) ISSUE(3)
    ISSUE(4) ISSUE(5) ISSUE(6) ISSUE(7)
    CONSUME(0) CONSUME(1) CONSUME(2) CONSUME(3)
    CONSUME(4) CONSUME(5) CONSUME(6) CONSUME(7)
  }

  // self term from own hl row (cache-hot)
  uint4 hwS = hl4[(size_t)i * 8 + s8];
  float scS = scaleArr[i];
  float hs[16];
  #pragma unroll
  for (int q = 0; q < 4; ++q) {
    uint32_t hword = q == 0 ? hwS.x : (q == 1 ? hwS.y : (q == 2 ? hwS.z : hwS.w));
    #pragma unroll
    for (int bj = 0; bj < 4; ++bj) hs[q * 4 + bj] = i8f(hword, 8 * bj) * scS;
  }

  float rr[16], ss[16], tt[16];
  #pragma unroll
  for (int q = 0; q < 4; ++q) {
    ((float4*)rr)[q] = ((const float4*)rootl)[s8 * 4 + q];
    ((float4*)ss)[q] = ((const float4*)sl)[s8 * 4 + q];
    ((float4*)tt)[q] = ((const float4*)tl)[s8 * 4 + q];
  }

  float o[16];
  #pragma unroll
  for (int j = 0; j < 16; ++j) {
    float self = fmaxf(hs[j] + rr[j], 0.f) * invdeg;
    o[j] = ss[j] * (self + a[j]) + tt[j];
  }

  if constexpr (!LAST) {
    #pragma unroll
    for (int j = 0; j < 16; ++j) o[j] = fmaxf(o[j], 0.f);
    uint4 p0, p1;
    p0.x = pk2(o[0], o[1]);   p0.y = pk2(o[2], o[3]);
    p0.z = pk2(o[4], o[5]);   p0.w = pk2(o[6], o[7]);
    p1.x = pk2(o[8], o[9]);   p1.y = pk2(o[10], o[11]);
    p1.z = pk2(o[12], o[13]); p1.w = pk2(o[14], o[15]);
    uint4* ap = (uint4*)acc + (size_t)i * 16 + s8 * 2;
    ap[0] = p0; ap[1] = p1;
  } else {
    int nd = perm[i];
    float4* ap = (float4*)acc + (size_t)nd * 32 + s8 * 4;
    ap[0] = make_float4(o[0], o[1], o[2], o[3]);
    ap[1] = make_float4(o[4], o[5], o[6], o[7]);
    ap[2] = make_float4(o[8], o[9], o[10], o[11]);
    ap[3] = make_float4(o[12], o[13], o[14], o[15]);
  }
}

// ---------------- launch ----------------
extern "C" void kernel_launch(void* const* d_in, const int* in_sizes, int n_in,
                              void* d_out, int out_size, void* d_ws, size_t ws_size,
                              hipStream_t stream) {
  const float* x     = (const float*)d_in[0];
  const int*   ei    = (const int*)d_in[1];
  const int*   ea    = (const int*)d_in[2];
  const float* W     = (const float*)d_in[3];
  const float* b     = (const float*)d_in[4];
  const float* root  = (const float*)d_in[5];
  const float* gamma = (const float*)d_in[6];
  const float* beta  = (const float*)d_in[7];
  const float* mean  = (const float*)d_in[8];
  const float* var   = (const float*)d_in[9];

  const int N = in_sizes[0] / DF;
  const int E = in_sizes[1] / 2;
  const int* row = ei;
  const int* col = ei + E;

  char* ws = (char*)d_ws;
  size_t off = 0;
  auto alloc = [&](size_t bytes) -> void* {
    void* p = ws + off;
    off = (off + bytes + 255) & ~(size_t)255;
    return p;
  };
  // zero-init group (one memset): degi, indeg, hist, binCursor
  int*      degi    = (int*)alloc((size_t)N * 4);
  int*      indeg   = (int*)alloc((size_t)N * 4);
  int*      hist    = (int*)alloc((size_t)NB * 4);
  int*      binCur  = (int*)alloc((size_t)NB * 4);
  size_t    zspan   = (size_t)((char*)ws + off - (char*)degi);
  float*    dinv    = (float*)alloc((size_t)N * 4);
  int*      nodeSt  = (int*)alloc((size_t)NB * 4);
  int*      edgeSt  = (int*)alloc((size_t)NB * 4);
  int*      perm    = (int*)alloc((size_t)N * 4);
  int*      invperm = (int*)alloc((size_t)N * 4);
  int*      startP  = (int*)alloc((size_t)N * 4);
  int*      cursorP = (int*)alloc((size_t)N * 4);
  int*      degP    = (int*)alloc((size_t)N * 4);
  float*    dinvP   = (float*)alloc((size_t)N * 4);
  int2*     pairS   = (int2*)alloc((size_t)E * 8);
  uint32_t* epS     = (uint32_t*)alloc((size_t)E * 8 * 4);
  float*    sbuf    = (float*)alloc((size_t)NL * DF * 4);
  float*    tbuf    = (float*)alloc((size_t)NL * DF * 4);
  ushort*   Wb      = (ushort*)alloc((size_t)NL * DF * DF * 2);
  uint8_t*  hl      = (uint8_t*)alloc((size_t)N * DF);
  float*    scaleA  = (float*)alloc((size_t)N * 4);
  ushort*   accP    = (ushort*)alloc((size_t)N * DF * 2);

  hipMemsetAsync(degi, 0, zspan, stream);

  k_deg2<<<(E + 255) / 256, 256, 0, stream>>>(row, col, degi, indeg, E);
  k_dinvhist<<<(N + 255) / 256, 256, 0, stream>>>(degi, indeg, dinv, hist, N);
  k_scan<<<1, NB, 0, stream>>>(hist, nodeSt, edgeSt);
  k_assign<<<(N + 255) / 256, 256, 0, stream>>>(indeg, dinv, nodeSt, edgeSt, binCur,
                                                perm, invperm, startP, cursorP,
                                                degP, dinvP, N);
  k_fillpack<<<(E * 8 + 255) / 256, 256, 0, stream>>>(row, col, dinv, invperm, cursorP,
                                                      pairS, ea, epS, E);
  k_params<<<(NL * DF * DF + 255) / 256, 256, 0, stream>>>(
      gamma, beta, mean, var, sbuf, tbuf, W, Wb, NL * DF, NL * DF * DF);

  float* outp = (float*)d_out;
  const int gemmGrid = (N + 127) / 128;
  const int gathGrid = (((N + 7) / 8) * 64 + 255) / 256;

  // layer 0: fp32 x (perm-indexed) -> hl; gather -> accP
  k_gemm<float><<<gemmGrid, 256, 0, stream>>>(x, perm, Wb, b, hl, scaleA, N);
  k_gather<ushort, false><<<gathGrid, 256, 0, stream>>>(
      startP, degP, dinvP, pairS, epS, (const uint4*)hl, scaleA,
      root, sbuf, tbuf, perm, accP, N);

  for (int l = 1; l < NL - 1; ++l) {
    k_gemm<ushort><<<gemmGrid, 256, 0, stream>>>(
        accP, nullptr, Wb + (size_t)l * DF * DF, b + (size_t)l * DF, hl, scaleA, N);
    k_gather<ushort, false><<<gathGrid, 256, 0, stream>>>(
        startP, degP, dinvP, pairS, epS, (const uint4*)hl, scaleA,
        root + (size_t)l * DF, sbuf + (size_t)l * DF, tbuf + (size_t)l * DF,
        perm, accP, N);
  }

  {
    const int l = NL - 1;
    k_gemm<ushort><<<gemmGrid, 256, 0, stream>>>(
        accP, nullptr, Wb + (size_t)l * DF * DF, b + (size_t)l * DF, hl, scaleA, N);
    k_gather<float, true><<<gathGrid, 256, 0, stream>>>(
        startP, degP, dinvP, pairS, epS, (const uint4*)hl, scaleA,
        root + (size_t)l * DF, sbuf + (size_t)l * DF, tbuf + (size_t)l * DF,
        perm, outp, N);
  }
}

// Round 11
// 424.968 us; speedup vs baseline: 1.1729x; 1.1729x over previous
//
#include <hip/hip_runtime.h>
#include <cstdint>
#include <cstddef>

#define DF 128
#define NL 5
#define NB 1024
#define BN_EPS 1e-5f

typedef short bf16x8 __attribute__((ext_vector_type(8)));
typedef float f32x4 __attribute__((ext_vector_type(4)));

typedef __attribute__((address_space(3))) uint32_t lds_u32;
typedef __attribute__((address_space(1))) uint32_t glb_u32;

__device__ __forceinline__ void gload16(const void* g, void* l) {
#if __has_builtin(__builtin_amdgcn_global_load_lds)
  __builtin_amdgcn_global_load_lds((const glb_u32*)g, (lds_u32*)l, 16, 0, 0);
#else
  *(uint4*)l = *(const uint4*)g;
#endif
}

// fp32 -> bf16 (RNE)
__device__ __forceinline__ ushort f2b(float f) {
  union { float f; uint32_t u; } v; v.f = f;
  uint32_t u = v.u + 0x7fffu + ((v.u >> 16) & 1u);
  return (ushort)(u >> 16);
}
__device__ __forceinline__ uint32_t pk2(float a, float b) {
  return (uint32_t)f2b(a) | ((uint32_t)f2b(b) << 16);
}
// signed int8 from byte `sh` of w, as float
__device__ __forceinline__ float i8f(uint32_t w, int sh) {
  return (float)(int8_t)((w >> sh) & 0xffu);
}

// ---------------- precompute ----------------

__global__ void k_deg2(const int* __restrict__ row, const int* __restrict__ col,
                       int* __restrict__ degi, int* __restrict__ indeg, int E) {
  int i = blockIdx.x * blockDim.x + threadIdx.x;
  if (i < E) {
    atomicAdd(&degi[row[i]], 1);
    atomicAdd(&indeg[col[i]], 1);
  }
}

__global__ void k_dinvhist(const int* __restrict__ degi, const int* __restrict__ indeg,
                           float* __restrict__ dinv, int* __restrict__ hist, int N) {
  __shared__ int lh[NB];
  for (int j = threadIdx.x; j < NB; j += blockDim.x) lh[j] = 0;
  __syncthreads();
  int i = blockIdx.x * blockDim.x + threadIdx.x;
  if (i < N) {
    dinv[i] = 1.0f / sqrtf((float)(degi[i] + 1));
    atomicAdd(&lh[min(indeg[i], NB - 1)], 1);
  }
  __syncthreads();
  for (int j = threadIdx.x; j < NB; j += blockDim.x) {
    int c = lh[j];
    if (c) atomicAdd(&hist[j], c);
  }
}

__global__ void k_scan(const int* __restrict__ hist,
                       int* __restrict__ nodeStart, int* __restrict__ edgeStart) {
  __shared__ int2 sm[NB];
  int t = threadIdx.x;
  int c = hist[t];
  int2 v; v.x = c; v.y = c * t;
  sm[t] = v;
  __syncthreads();
  for (int off = 1; off < NB; off <<= 1) {
    int2 add; add.x = 0; add.y = 0;
    if (t >= off) add = sm[t - off];
    __syncthreads();
    sm[t].x += add.x; sm[t].y += add.y;
    __syncthreads();
  }
  nodeStart[t] = sm[t].x - c;
  edgeStart[t] = sm[t].y - c * t;
}

__global__ void k_assign(const int* __restrict__ indeg, const float* __restrict__ dinv,
                         const int* __restrict__ nodeStart, const int* __restrict__ edgeStart,
                         int* __restrict__ binCursor,
                         int* __restrict__ perm, int* __restrict__ invperm,
                         int* __restrict__ startP, int* __restrict__ cursorP,
                         int* __restrict__ degP, float* __restrict__ dinvP, int N) {
  __shared__ int lh[NB];
  __shared__ int gbase[NB];
  for (int j = threadIdx.x; j < NB; j += blockDim.x) lh[j] = 0;
  __syncthreads();
  int nd = blockIdx.x * blockDim.x + threadIdx.x;
  bool valid = nd < N;
  int d = 0, bin = 0, lrank = 0;
  if (valid) {
    d = indeg[nd];
    bin = min(d, NB - 1);
    lrank = atomicAdd(&lh[bin], 1);
  }
  __syncthreads();
  for (int j = threadIdx.x; j < NB; j += blockDim.x) {
    int c = lh[j];
    gbase[j] = c ? atomicAdd(&binCursor[j], c) : 0;
  }
  __syncthreads();
  if (!valid) return;
  int r = gbase[bin] + lrank;
  int i = nodeStart[bin] + r;
  perm[i] = nd;
  invperm[nd] = i;
  int st = edgeStart[bin] + r * d;
  startP[i] = st;
  cursorP[i] = st;
  degP[i] = d;
  dinvP[i] = dinv[nd];
}

__global__ void k_fillpack(const int* __restrict__ row, const int* __restrict__ col,
                           const float* __restrict__ dinv, const int* __restrict__ invperm,
                           int* __restrict__ cursorP, int2* __restrict__ pairS,
                           const int* __restrict__ ea, uint32_t* __restrict__ epS, int E) {
  int tid = blockIdx.x * blockDim.x + threadIdx.x;
  int e = tid >> 3, t = tid & 7;
  if (e >= E) return;
  int pos;
  if (t == 0) {
    int r = row[e], c = col[e];
    pos = atomicAdd(&cursorP[invperm[c]], 1);
    int2 pv; pv.x = invperm[r];
    float nr = dinv[r] * dinv[c];
    pv.y = __float_as_int(nr);
    pairS[pos] = pv;
  }
  pos = __shfl(pos, 0, 8);
  const int4* p = ((const int4*)ea) + (size_t)e * 32 + t * 4;
  uint32_t w = 0;
  #pragma unroll
  for (int q = 0; q < 4; ++q) {
    int4 a = p[q];
    w |= ((uint32_t)(a.x & 3)) << (8 * q);
    w |= ((uint32_t)(a.y & 3)) << (8 * q + 2);
    w |= ((uint32_t)(a.z & 3)) << (8 * q + 4);
    w |= ((uint32_t)(a.w & 3)) << (8 * q + 6);
  }
  epS[(size_t)pos * 8 + t] = w;
}

__global__ void k_params(const float* __restrict__ g, const float* __restrict__ be,
                         const float* __restrict__ mn, const float* __restrict__ vr,
                         float* __restrict__ s, float* __restrict__ t,
                         const float* __restrict__ W, ushort* __restrict__ Wb,
                         int nbn, int nw) {
  int i = blockIdx.x * blockDim.x + threadIdx.x;
  if (i < nw) Wb[i] = f2b(W[i]);
  if (i < nbn) {
    float sc = g[i] / sqrtf(vr[i] + BN_EPS);
    s[i] = sc;
    t[i] = be[i] - mn[i] * sc;
  }
}

// ---------------- layer-0 GEMM: hl0(int8+scale) = x[perm] @ W0^T + b0 ----------------
__global__ __launch_bounds__(256) void k_gemm0(
    const float* __restrict__ in, const int* __restrict__ perm,
    const ushort* __restrict__ Wb, const float* __restrict__ bl,
    uint8_t* __restrict__ hl, float* __restrict__ scale, int N)
{
  __shared__ uint4 lA[128 * 16];
  __shared__ uint4 lW[128 * 16];
  const int t = threadIdx.x;
  const int row0 = blockIdx.x * 128;
  const int wv = t >> 6;
  const int l  = t & 63;

  #pragma unroll
  for (int it = 0; it < 8; ++it) {
    int ubase = (it * 4 + wv) * 64;
    int lin = ubase + l;
    int r = lin >> 4, u = lin & 15;
    gload16((const void*)((const uint4*)Wb + (r << 4) + (u ^ (r & 7))), (void*)(lW + ubase));
  }
  #pragma unroll
  for (int it = 0; it < 8; ++it) {
    int lin = it * 256 + t;
    int r = lin >> 4, u = lin & 15;
    int gn = row0 + r;
    uint4 pk = make_uint4(0u, 0u, 0u, 0u);
    if (gn < N) {
      int src = perm[gn];
      const float4* p = (const float4*)(in + (size_t)src * DF + u * 8);
      float4 f0 = p[0], f1 = p[1];
      pk.x = pk2(f0.x, f0.y); pk.y = pk2(f0.z, f0.w);
      pk.z = pk2(f1.x, f1.y); pk.w = pk2(f1.z, f1.w);
    }
    lA[(r << 4) | (u ^ (r & 7))] = pk;
  }
  __syncthreads();

  const int lr = l & 15;
  const int lk = l >> 4;

  f32x4 acc[2][8];
  #pragma unroll
  for (int rt = 0; rt < 2; ++rt)
    #pragma unroll
    for (int ct = 0; ct < 8; ++ct) acc[rt][ct] = (f32x4){0.f, 0.f, 0.f, 0.f};

  #pragma unroll
  for (int ks = 0; ks < 4; ++ks) {
    const int kofs = ks * 4 + lk;
    bf16x8 af[2], wf[8];
    #pragma unroll
    for (int rt = 0; rt < 2; ++rt) {
      int r = wv * 32 + rt * 16 + lr;
      af[rt] = *reinterpret_cast<const bf16x8*>(&lA[(r << 4) | (kofs ^ (r & 7))]);
    }
    #pragma unroll
    for (int ct = 0; ct < 8; ++ct) {
      int r = ct * 16 + lr;
      wf[ct] = *reinterpret_cast<const bf16x8*>(&lW[(r << 4) | (kofs ^ (r & 7))]);
    }
    #pragma unroll
    for (int rt = 0; rt < 2; ++rt)
      #pragma unroll
      for (int ct = 0; ct < 8; ++ct)
        acc[rt][ct] = __builtin_amdgcn_mfma_f32_16x16x32_bf16(af[rt], wf[ct], acc[rt][ct], 0, 0, 0);
  }

  float bb[8];
  #pragma unroll
  for (int ct = 0; ct < 8; ++ct) bb[ct] = bl[ct * 16 + lr];

  __syncthreads();
  uint8_t* q8 = (uint8_t*)lA;

  #pragma unroll
  for (int rt = 0; rt < 2; ++rt) {
    #pragma unroll
    for (int rg = 0; rg < 4; ++rg) {
      int rloc = wv * 32 + rt * 16 + lk * 4 + rg;
      float o[8];
      float am = 0.f;
      #pragma unroll
      for (int ct = 0; ct < 8; ++ct) {
        o[ct] = acc[rt][ct][rg] + bb[ct];
        am = fmaxf(am, fabsf(o[ct]));
      }
      am = fmaxf(am, __shfl_xor(am, 1));
      am = fmaxf(am, __shfl_xor(am, 2));
      am = fmaxf(am, __shfl_xor(am, 4));
      am = fmaxf(am, __shfl_xor(am, 8));
      float inv = am > 0.f ? 127.f / am : 0.f;
      int gn = row0 + rloc;
      if (lr == 0 && gn < N) scale[gn] = am * (1.f / 127.f);
      #pragma unroll
      for (int ct = 0; ct < 8; ++ct) {
        int q = __float2int_rn(o[ct] * inv);
        q8[rloc * DF + ct * 16 + lr] = (uint8_t)(q & 0xff);
      }
    }
  }
  __syncthreads();

  #pragma unroll
  for (int it = 0; it < 8; ++it) {
    int chunk = it * 256 + t;
    int rloc = chunk >> 4;
    int gn = row0 + rloc;
    if (gn < N) {
      uint2 v = *(const uint2*)(q8 + chunk * 8);
      *(uint2*)(hl + (size_t)gn * DF + (chunk & 15) * 8) = v;
    }
  }
}

// ---------------- FUSED: gather(layer l) + GEMM(layer l+1) ----------------
// 512 threads, 128 permuted nodes/block.
// Phase 1 (gather): 8 lanes/node, R8-style loop; o = relu(BN(self + msgs)),
// packed bf16 straight into the GEMM A-tile in LDS (swizzled).
// Phase 2 (MFMA, 8 waves x 16 rows): hlOut = A @ W^T + b, int8-quantized.
// W staging is issued BEFORE the gather -> hidden under gather latency.
__global__ __launch_bounds__(512, 4) void k_fused(
    const int* __restrict__ startP, const int* __restrict__ degP,
    const float* __restrict__ dinvP,
    const int2* __restrict__ pairS, const uint32_t* __restrict__ epS,
    const uint4* __restrict__ hlIn, const float* __restrict__ scaleIn,
    const float* __restrict__ rootl, const float* __restrict__ sl,
    const float* __restrict__ tl,
    const ushort* __restrict__ Wb, const float* __restrict__ bl,
    uint8_t* __restrict__ hlOut, float* __restrict__ scaleOut, int N)
{
  __shared__ uint4 lA[128 * 16];
  __shared__ uint4 lW[128 * 16];
  const int t = threadIdx.x;
  const int row0 = blockIdx.x * 128;
  const int wv = t >> 6;     // 0..7
  const int l  = t & 63;

  // stage W for next layer (async; completes under the gather)
  #pragma unroll
  for (int it = 0; it < 4; ++it) {
    int ubase = (it * 8 + wv) * 64;
    int lin = ubase + l;
    int r = lin >> 4, u = lin & 15;
    gload16((const void*)((const uint4*)Wb + (r << 4) + (u ^ (r & 7))), (void*)(lW + ubase));
  }

  // ---- phase 1: gather ----
  const int s8 = t & 7;
  const int nib = t >> 3;    // 0..63
  #pragma unroll
  for (int pass = 0; pass < 2; ++pass) {
    int r = pass * 64 + nib;       // 0..127
    int i = row0 + r;
    float o[16];
    if (i < N) {
      int base = startP[i], n = degP[i];
      float di = dinvP[i];
      float invdeg = di * di;
      float a[16];
      #pragma unroll
      for (int j = 0; j < 16; ++j) a[j] = 0.f;

      for (int c0 = 0; c0 < n; c0 += 8) {
        int m = min(8, n - c0);
        int2 pv = (s8 < m) ? pairS[base + c0 + s8] : make_int2(0, 0);
        #pragma unroll 2
        for (int k = 0; k < m; ++k) {
          int src = __shfl(pv.x, k, 8);
          float nr = __int_as_float(__shfl(pv.y, k, 8));
          uint32_t pw = epS[(size_t)(base + c0 + k) * 8 + s8];
          uint4 hw = hlIn[(size_t)src * 8 + s8];
          float sc = scaleIn[src];
          #pragma unroll
          for (int q = 0; q < 4; ++q) {
            uint32_t hword = q == 0 ? hw.x : (q == 1 ? hw.y : (q == 2 ? hw.z : hw.w));
            #pragma unroll
            for (int bj = 0; bj < 4; ++bj) {
              int j = q * 4 + bj;
              float ev = (float)((pw >> (2 * j)) & 3u);
              a[j] += nr * fmaxf(fmaf(i8f(hword, 8 * bj), sc, ev), 0.f);
            }
          }
        }
      }

      uint4 hwS = hlIn[(size_t)i * 8 + s8];
      float scS = scaleIn[i];
      float hs[16];
      #pragma unroll
      for (int q = 0; q < 4; ++q) {
        uint32_t hword = q == 0 ? hwS.x : (q == 1 ? hwS.y : (q == 2 ? hwS.z : hwS.w));
        #pragma unroll
        for (int bj = 0; bj < 4; ++bj) hs[q * 4 + bj] = i8f(hword, 8 * bj) * scS;
      }

      float rr[16], ss[16], tt[16];
      #pragma unroll
      for (int q = 0; q < 4; ++q) {
        ((float4*)rr)[q] = ((const float4*)rootl)[s8 * 4 + q];
        ((float4*)ss)[q] = ((const float4*)sl)[s8 * 4 + q];
        ((float4*)tt)[q] = ((const float4*)tl)[s8 * 4 + q];
      }
      #pragma unroll
      for (int j = 0; j < 16; ++j) {
        float self = fmaxf(hs[j] + rr[j], 0.f) * invdeg;
        o[j] = fmaxf(ss[j] * (self + a[j]) + tt[j], 0.f);   // inter-layer relu folded
      }
    } else {
      #pragma unroll
      for (int j = 0; j < 16; ++j) o[j] = 0.f;
    }

    // pack bf16 -> A-tile (units 2*s8, 2*s8+1 of row r, swizzled)
    uint4 p0, p1;
    p0.x = pk2(o[0], o[1]);   p0.y = pk2(o[2], o[3]);
    p0.z = pk2(o[4], o[5]);   p0.w = pk2(o[6], o[7]);
    p1.x = pk2(o[8], o[9]);   p1.y = pk2(o[10], o[11]);
    p1.z = pk2(o[12], o[13]); p1.w = pk2(o[14], o[15]);
    int u0 = 2 * s8, u1 = 2 * s8 + 1;
    lA[(r << 4) | (u0 ^ (r & 7))] = p0;
    lA[(r << 4) | (u1 ^ (r & 7))] = p1;
  }
  __syncthreads();   // A-tile complete; W loads drained (vmcnt 0 before barrier)

  // ---- phase 2: MFMA (8 waves x 16 rows each) ----
  const int lr = l & 15;
  const int lk = l >> 4;

  f32x4 acc[8];
  #pragma unroll
  for (int ct = 0; ct < 8; ++ct) acc[ct] = (f32x4){0.f, 0.f, 0.f, 0.f};

  #pragma unroll
  for (int ks = 0; ks < 4; ++ks) {
    const int kofs = ks * 4 + lk;
    bf16x8 af, wf[8];
    {
      int r = wv * 16 + lr;
      af = *reinterpret_cast<const bf16x8*>(&lA[(r << 4) | (kofs ^ (r & 7))]);
    }
    #pragma unroll
    for (int ct = 0; ct < 8; ++ct) {
      int r = ct * 16 + lr;
      wf[ct] = *reinterpret_cast<const bf16x8*>(&lW[(r << 4) | (kofs ^ (r & 7))]);
    }
    #pragma unroll
    for (int ct = 0; ct < 8; ++ct)
      acc[ct] = __builtin_amdgcn_mfma_f32_16x16x32_bf16(af, wf[ct], acc[ct], 0, 0, 0);
  }

  float bb[8];
  #pragma unroll
  for (int ct = 0; ct < 8; ++ct) bb[ct] = bl[ct * 16 + lr];

  __syncthreads();
  uint8_t* q8 = (uint8_t*)lA;

  #pragma unroll
  for (int rg = 0; rg < 4; ++rg) {
    int rloc = wv * 16 + lk * 4 + rg;
    float o[8];
    float am = 0.f;
    #pragma unroll
    for (int ct = 0; ct < 8; ++ct) {
      o[ct] = acc[ct][rg] + bb[ct];
      am = fmaxf(am, fabsf(o[ct]));
    }
    am = fmaxf(am, __shfl_xor(am, 1));
    am = fmaxf(am, __shfl_xor(am, 2));
    am = fmaxf(am, __shfl_xor(am, 4));
    am = fmaxf(am, __shfl_xor(am, 8));
    float inv = am > 0.f ? 127.f / am : 0.f;
    int gn = row0 + rloc;
    if (lr == 0 && gn < N) scaleOut[gn] = am * (1.f / 127.f);
    #pragma unroll
    for (int ct = 0; ct < 8; ++ct) {
      int q = __float2int_rn(o[ct] * inv);
      q8[rloc * DF + ct * 16 + lr] = (uint8_t)(q & 0xff);
    }
  }
  __syncthreads();

  #pragma unroll
  for (int it = 0; it < 4; ++it) {
    int chunk = it * 512 + t;
    int rloc = chunk >> 4;
    int gn = row0 + rloc;
    if (gn < N) {
      uint2 v = *(const uint2*)(q8 + chunk * 8);
      *(uint2*)(hlOut + (size_t)gn * DF + (chunk & 15) * 8) = v;
    }
  }
}

// ---------------- final gather (layer 4) -> fp32 d_out[perm] ----------------
__global__ __launch_bounds__(256) void k_gather_last(
    const int* __restrict__ startP, const int* __restrict__ degP,
    const float* __restrict__ dinvP,
    const int2* __restrict__ pairS,
    const uint32_t* __restrict__ epS,
    const uint4* __restrict__ hl4, const float* __restrict__ scaleArr,
    const float* __restrict__ rootl, const float* __restrict__ sl,
    const float* __restrict__ tl, const int* __restrict__ perm,
    float* __restrict__ acc, int N)
{
  int gw = (blockIdx.x * blockDim.x + threadIdx.x) >> 6;
  int lane = threadIdx.x & 63;
  int s8 = lane & 7;
  int i = gw * 8 + (lane >> 3);
  if (i >= N) return;
  int base = startP[i], n = degP[i];
  float di = dinvP[i];
  float invdeg = di * di;

  float a[16];
  #pragma unroll
  for (int j = 0; j < 16; ++j) a[j] = 0.f;

  for (int c0 = 0; c0 < n; c0 += 8) {
    int m = min(8, n - c0);
    int2 pv = (s8 < m) ? pairS[base + c0 + s8] : make_int2(0, 0);
    #pragma unroll 2
    for (int k = 0; k < m; ++k) {
      int src = __shfl(pv.x, k, 8);
      float nr = __int_as_float(__shfl(pv.y, k, 8));
      uint32_t pw = epS[(size_t)(base + c0 + k) * 8 + s8];
      uint4 hw = hl4[(size_t)src * 8 + s8];
      float sc = scaleArr[src];
      #pragma unroll
      for (int q = 0; q < 4; ++q) {
        uint32_t hword = q == 0 ? hw.x : (q == 1 ? hw.y : (q == 2 ? hw.z : hw.w));
        #pragma unroll
        for (int bj = 0; bj < 4; ++bj) {
          int j = q * 4 + bj;
          float ev = (float)((pw >> (2 * j)) & 3u);
          a[j] += nr * fmaxf(fmaf(i8f(hword, 8 * bj), sc, ev), 0.f);
        }
      }
    }
  }

  uint4 hwS = hl4[(size_t)i * 8 + s8];
  float scS = scaleArr[i];
  float hs[16];
  #pragma unroll
  for (int q = 0; q < 4; ++q) {
    uint32_t hword = q == 0 ? hwS.x : (q == 1 ? hwS.y : (q == 2 ? hwS.z : hwS.w));
    #pragma unroll
    for (int bj = 0; bj < 4; ++bj) hs[q * 4 + bj] = i8f(hword, 8 * bj) * scS;
  }

  float rr[16], ss[16], tt[16];
  #pragma unroll
  for (int q = 0; q < 4; ++q) {
    ((float4*)rr)[q] = ((const float4*)rootl)[s8 * 4 + q];
    ((float4*)ss)[q] = ((const float4*)sl)[s8 * 4 + q];
    ((float4*)tt)[q] = ((const float4*)tl)[s8 * 4 + q];
  }

  float o[16];
  #pragma unroll
  for (int j = 0; j < 16; ++j) {
    float self = fmaxf(hs[j] + rr[j], 0.f) * invdeg;
    o[j] = ss[j] * (self + a[j]) + tt[j];
  }

  int nd = perm[i];
  float4* ap = (float4*)acc + (size_t)nd * 32 + s8 * 4;
  ap[0] = make_float4(o[0], o[1], o[2], o[3]);
  ap[1] = make_float4(o[4], o[5], o[6], o[7]);
  ap[2] = make_float4(o[8], o[9], o[10], o[11]);
  ap[3] = make_float4(o[12], o[13], o[14], o[15]);
}

// ---------------- launch ----------------
extern "C" void kernel_launch(void* const* d_in, const int* in_sizes, int n_in,
                              void* d_out, int out_size, void* d_ws, size_t ws_size,
                              hipStream_t stream) {
  const float* x     = (const float*)d_in[0];
  const int*   ei    = (const int*)d_in[1];
  const int*   ea    = (const int*)d_in[2];
  const float* W     = (const float*)d_in[3];
  const float* b     = (const float*)d_in[4];
  const float* root  = (const float*)d_in[5];
  const float* gamma = (const float*)d_in[6];
  const float* beta  = (const float*)d_in[7];
  const float* mean  = (const float*)d_in[8];
  const float* var   = (const float*)d_in[9];

  const int N = in_sizes[0] / DF;
  const int E = in_sizes[1] / 2;
  const int* row = ei;
  const int* col = ei + E;

  char* ws = (char*)d_ws;
  size_t off = 0;
  auto alloc = [&](size_t bytes) -> void* {
    void* p = ws + off;
    off = (off + bytes + 255) & ~(size_t)255;
    return p;
  };
  int*      degi    = (int*)alloc((size_t)N * 4);
  int*      indeg   = (int*)alloc((size_t)N * 4);
  int*      hist    = (int*)alloc((size_t)NB * 4);
  int*      binCur  = (int*)alloc((size_t)NB * 4);
  size_t    zspan   = (size_t)((char*)ws + off - (char*)degi);
  float*    dinv    = (float*)alloc((size_t)N * 4);
  int*      nodeSt  = (int*)alloc((size_t)NB * 4);
  int*      edgeSt  = (int*)alloc((size_t)NB * 4);
  int*      perm    = (int*)alloc((size_t)N * 4);
  int*      invperm = (int*)alloc((size_t)N * 4);
  int*      startP  = (int*)alloc((size_t)N * 4);
  int*      cursorP = (int*)alloc((size_t)N * 4);
  int*      degP    = (int*)alloc((size_t)N * 4);
  float*    dinvP   = (float*)alloc((size_t)N * 4);
  int2*     pairS   = (int2*)alloc((size_t)E * 8);
  uint32_t* epS     = (uint32_t*)alloc((size_t)E * 8 * 4);
  float*    sbuf    = (float*)alloc((size_t)NL * DF * 4);
  float*    tbuf    = (float*)alloc((size_t)NL * DF * 4);
  ushort*   Wb      = (ushort*)alloc((size_t)NL * DF * DF * 2);
  uint8_t*  hlA     = (uint8_t*)alloc((size_t)N * DF);
  uint8_t*  hlB     = (uint8_t*)alloc((size_t)N * DF);
  float*    scA     = (float*)alloc((size_t)N * 4);
  float*    scB     = (float*)alloc((size_t)N * 4);

  hipMemsetAsync(degi, 0, zspan, stream);

  k_deg2<<<(E + 255) / 256, 256, 0, stream>>>(row, col, degi, indeg, E);
  k_dinvhist<<<(N + 255) / 256, 256, 0, stream>>>(degi, indeg, dinv, hist, N);
  k_scan<<<1, NB, 0, stream>>>(hist, nodeSt, edgeSt);
  k_assign<<<(N + 255) / 256, 256, 0, stream>>>(indeg, dinv, nodeSt, edgeSt, binCur,
                                                perm, invperm, startP, cursorP,
                                                degP, dinvP, N);
  k_fillpack<<<(E * 8 + 255) / 256, 256, 0, stream>>>(row, col, dinv, invperm, cursorP,
                                                      pairS, ea, epS, E);
  k_params<<<(NL * DF * DF + 255) / 256, 256, 0, stream>>>(
      gamma, beta, mean, var, sbuf, tbuf, W, Wb, NL * DF, NL * DF * DF);

  float* outp = (float*)d_out;
  const int tiles = (N + 127) / 128;

  // layer 0 GEMM: x -> hlA/scA
  k_gemm0<<<tiles, 256, 0, stream>>>(x, perm, Wb, b, hlA, scA, N);

  // fused gather(l) + gemm(l+1), l = 0..3; hl ping-pong A->B->A->B->A
  uint8_t* hin = hlA; float* sin_ = scA;
  uint8_t* hout = hlB; float* sout = scB;
  for (int l = 0; l < NL - 1; ++l) {
    k_fused<<<tiles, 512, 0, stream>>>(
        startP, degP, dinvP, pairS, epS,
        (const uint4*)hin, sin_,
        root + (size_t)l * DF, sbuf + (size_t)l * DF, tbuf + (size_t)l * DF,
        Wb + (size_t)(l + 1) * DF * DF, b + (size_t)(l + 1) * DF,
        hout, sout, N);
    uint8_t* th = hin; hin = hout; hout = th;
    float* ts = sin_; sin_ = sout; sout = ts;
  }

  // final gather (layer 4) -> d_out
  {
    const int l = NL - 1;
    k_gather_last<<<(((N + 7) / 8) * 64 + 255) / 256, 256, 0, stream>>>(
        startP, degP, dinvP, pairS, epS, (const uint4*)hin, sin_,
        root + (size_t)l * DF, sbuf + (size_t)l * DF, tbuf + (size_t)l * DF,
        perm, outp, N);
  }
}

// Round 12
// 402.428 us; speedup vs baseline: 1.2386x; 1.0560x over previous
//
#include <hip/hip_runtime.h>
#include <cstdint>
#include <cstddef>

#define DF 128
#define NL 5
#define NB 1024
#define BN_EPS 1e-5f

typedef short bf16x8 __attribute__((ext_vector_type(8)));
typedef float f32x4 __attribute__((ext_vector_type(4)));

typedef __attribute__((address_space(3))) uint32_t lds_u32;
typedef __attribute__((address_space(1))) uint32_t glb_u32;

__device__ __forceinline__ void gload16(const void* g, void* l) {
#if __has_builtin(__builtin_amdgcn_global_load_lds)
  __builtin_amdgcn_global_load_lds((const glb_u32*)g, (lds_u32*)l, 16, 0, 0);
#else
  *(uint4*)l = *(const uint4*)g;
#endif
}

// fp32 -> bf16 (RNE)
__device__ __forceinline__ ushort f2b(float f) {
  union { float f; uint32_t u; } v; v.f = f;
  uint32_t u = v.u + 0x7fffu + ((v.u >> 16) & 1u);
  return (ushort)(u >> 16);
}
__device__ __forceinline__ uint32_t pk2(float a, float b) {
  return (uint32_t)f2b(a) | ((uint32_t)f2b(b) << 16);
}
// signed int8 from byte `sh` of w, as float
__device__ __forceinline__ float i8f(uint32_t w, int sh) {
  return (float)(int8_t)((w >> sh) & 0xffu);
}

// ---------------- precompute ----------------

// 2 edges per thread (int2 loads) — same atomics, half the waves.
__global__ void k_deg2(const int* __restrict__ row, const int* __restrict__ col,
                       int* __restrict__ degi, int* __restrict__ indeg, int E) {
  int i = blockIdx.x * blockDim.x + threadIdx.x;
  int e0 = i * 2;
  if (e0 + 1 < E) {
    int2 r2 = *(const int2*)(row + e0);
    int2 c2 = *(const int2*)(col + e0);
    atomicAdd(&degi[r2.x], 1);
    atomicAdd(&degi[r2.y], 1);
    atomicAdd(&indeg[c2.x], 1);
    atomicAdd(&indeg[c2.y], 1);
  } else if (e0 < E) {
    atomicAdd(&degi[row[e0]], 1);
    atomicAdd(&indeg[col[e0]], 1);
  }
}

// dinv + in-degree histogram (two-level: LDS histogram, one global add per bin/block)
__global__ void k_dinvhist(const int* __restrict__ degi, const int* __restrict__ indeg,
                           float* __restrict__ dinv, int* __restrict__ hist, int N) {
  __shared__ int lh[NB];
  for (int j = threadIdx.x; j < NB; j += blockDim.x) lh[j] = 0;
  __syncthreads();
  int i = blockIdx.x * blockDim.x + threadIdx.x;
  if (i < N) {
    dinv[i] = 1.0f / sqrtf((float)(degi[i] + 1));
    atomicAdd(&lh[min(indeg[i], NB - 1)], 1);
  }
  __syncthreads();
  for (int j = threadIdx.x; j < NB; j += blockDim.x) {
    int c = lh[j];
    if (c) atomicAdd(&hist[j], c);
  }
}

__global__ void k_scan(const int* __restrict__ hist,
                       int* __restrict__ nodeStart, int* __restrict__ edgeStart) {
  __shared__ int2 sm[NB];
  int t = threadIdx.x;
  int c = hist[t];
  int2 v; v.x = c; v.y = c * t;
  sm[t] = v;
  __syncthreads();
  for (int off = 1; off < NB; off <<= 1) {
    int2 add; add.x = 0; add.y = 0;
    if (t >= off) add = sm[t - off];
    __syncthreads();
    sm[t].x += add.x; sm[t].y += add.y;
    __syncthreads();
  }
  nodeStart[t] = sm[t].x - c;
  edgeStart[t] = sm[t].y - c * t;
}

__global__ void k_assign(const int* __restrict__ indeg, const float* __restrict__ dinv,
                         const int* __restrict__ nodeStart, const int* __restrict__ edgeStart,
                         int* __restrict__ binCursor,
                         int* __restrict__ perm, int* __restrict__ invperm,
                         int* __restrict__ startP, int* __restrict__ cursorP,
                         int* __restrict__ degP, float* __restrict__ dinvP, int N) {
  __shared__ int lh[NB];
  __shared__ int gbase[NB];
  for (int j = threadIdx.x; j < NB; j += blockDim.x) lh[j] = 0;
  __syncthreads();
  int nd = blockIdx.x * blockDim.x + threadIdx.x;
  bool valid = nd < N;
  int d = 0, bin = 0, lrank = 0;
  if (valid) {
    d = indeg[nd];
    bin = min(d, NB - 1);
    lrank = atomicAdd(&lh[bin], 1);
  }
  __syncthreads();
  for (int j = threadIdx.x; j < NB; j += blockDim.x) {
    int c = lh[j];
    gbase[j] = c ? atomicAdd(&binCursor[j], c) : 0;
  }
  __syncthreads();
  if (!valid) return;
  int r = gbase[bin] + lrank;
  int i = nodeStart[bin] + r;
  perm[i] = nd;
  invperm[nd] = i;
  int st = edgeStart[bin] + r * d;
  startP[i] = st;
  cursorP[i] = st;
  degP[i] = d;
  dinvP[i] = dinv[nd];
}

__global__ void k_fillpack(const int* __restrict__ row, const int* __restrict__ col,
                           const float* __restrict__ dinv, const int* __restrict__ invperm,
                           int* __restrict__ cursorP, int2* __restrict__ pairS,
                           const int* __restrict__ ea, uint32_t* __restrict__ epS, int E) {
  int tid = blockIdx.x * blockDim.x + threadIdx.x;
  int e = tid >> 3, t = tid & 7;
  if (e >= E) return;
  int pos;
  if (t == 0) {
    int r = row[e], c = col[e];
    pos = atomicAdd(&cursorP[invperm[c]], 1);
    int2 pv; pv.x = invperm[r];
    float nr = dinv[r] * dinv[c];
    pv.y = __float_as_int(nr);
    pairS[pos] = pv;
  }
  pos = __shfl(pos, 0, 8);
  const int4* p = ((const int4*)ea) + (size_t)e * 32 + t * 4;
  uint32_t w = 0;
  #pragma unroll
  for (int q = 0; q < 4; ++q) {
    int4 a = p[q];
    w |= ((uint32_t)(a.x & 3)) << (8 * q);
    w |= ((uint32_t)(a.y & 3)) << (8 * q + 2);
    w |= ((uint32_t)(a.z & 3)) << (8 * q + 4);
    w |= ((uint32_t)(a.w & 3)) << (8 * q + 6);
  }
  epS[(size_t)pos * 8 + t] = w;
}

__global__ void k_params(const float* __restrict__ g, const float* __restrict__ be,
                         const float* __restrict__ mn, const float* __restrict__ vr,
                         float* __restrict__ s, float* __restrict__ t,
                         const float* __restrict__ W, ushort* __restrict__ Wb,
                         int nbn, int nw) {
  int i = blockIdx.x * blockDim.x + threadIdx.x;
  if (i < nw) Wb[i] = f2b(W[i]);
  if (i < nbn) {
    float sc = g[i] / sqrtf(vr[i] + BN_EPS);
    s[i] = sc;
    t[i] = be[i] - mn[i] * sc;
  }
}

// ---------------- layer-0 GEMM: hl[invperm[r]] = x[r] @ W0^T + b0 ----------------
// Reads x SEQUENTIALLY (row-block), scatters output rows via invperm.
// (Scattered 128B full-line writes are write-combined; replaces 100k random
// 512B x-row reads with 100k scattered row writes.)
__global__ __launch_bounds__(256) void k_gemm0(
    const float* __restrict__ in, const int* __restrict__ invperm,
    const ushort* __restrict__ Wb, const float* __restrict__ bl,
    uint8_t* __restrict__ hl, float* __restrict__ scale, int N)
{
  __shared__ uint4 lA[128 * 16];
  __shared__ uint4 lW[128 * 16];
  const int t = threadIdx.x;
  const int row0 = blockIdx.x * 128;
  const int wv = t >> 6;
  const int l  = t & 63;

  #pragma unroll
  for (int it = 0; it < 8; ++it) {
    int ubase = (it * 4 + wv) * 64;
    int lin = ubase + l;
    int r = lin >> 4, u = lin & 15;
    gload16((const void*)((const uint4*)Wb + (r << 4) + (u ^ (r & 7))), (void*)(lW + ubase));
  }
  #pragma unroll
  for (int it = 0; it < 8; ++it) {
    int lin = it * 256 + t;
    int r = lin >> 4, u = lin & 15;
    int gn = row0 + r;
    uint4 pk = make_uint4(0u, 0u, 0u, 0u);
    if (gn < N) {
      const float4* p = (const float4*)(in + (size_t)gn * DF + u * 8);
      float4 f0 = p[0], f1 = p[1];
      pk.x = pk2(f0.x, f0.y); pk.y = pk2(f0.z, f0.w);
      pk.z = pk2(f1.x, f1.y); pk.w = pk2(f1.z, f1.w);
    }
    lA[(r << 4) | (u ^ (r & 7))] = pk;
  }
  __syncthreads();

  const int lr = l & 15;
  const int lk = l >> 4;

  f32x4 acc[2][8];
  #pragma unroll
  for (int rt = 0; rt < 2; ++rt)
    #pragma unroll
    for (int ct = 0; ct < 8; ++ct) acc[rt][ct] = (f32x4){0.f, 0.f, 0.f, 0.f};

  #pragma unroll
  for (int ks = 0; ks < 4; ++ks) {
    const int kofs = ks * 4 + lk;
    bf16x8 af[2], wf[8];
    #pragma unroll
    for (int rt = 0; rt < 2; ++rt) {
      int r = wv * 32 + rt * 16 + lr;
      af[rt] = *reinterpret_cast<const bf16x8*>(&lA[(r << 4) | (kofs ^ (r & 7))]);
    }
    #pragma unroll
    for (int ct = 0; ct < 8; ++ct) {
      int r = ct * 16 + lr;
      wf[ct] = *reinterpret_cast<const bf16x8*>(&lW[(r << 4) | (kofs ^ (r & 7))]);
    }
    #pragma unroll
    for (int rt = 0; rt < 2; ++rt)
      #pragma unroll
      for (int ct = 0; ct < 8; ++ct)
        acc[rt][ct] = __builtin_amdgcn_mfma_f32_16x16x32_bf16(af[rt], wf[ct], acc[rt][ct], 0, 0, 0);
  }

  float bb[8];
  #pragma unroll
  for (int ct = 0; ct < 8; ++ct) bb[ct] = bl[ct * 16 + lr];

  __syncthreads();
  uint8_t* q8 = (uint8_t*)lA;

  #pragma unroll
  for (int rt = 0; rt < 2; ++rt) {
    #pragma unroll
    for (int rg = 0; rg < 4; ++rg) {
      int rloc = wv * 32 + rt * 16 + lk * 4 + rg;
      float o[8];
      float am = 0.f;
      #pragma unroll
      for (int ct = 0; ct < 8; ++ct) {
        o[ct] = acc[rt][ct][rg] + bb[ct];
        am = fmaxf(am, fabsf(o[ct]));
      }
      am = fmaxf(am, __shfl_xor(am, 1));
      am = fmaxf(am, __shfl_xor(am, 2));
      am = fmaxf(am, __shfl_xor(am, 4));
      am = fmaxf(am, __shfl_xor(am, 8));
      float inv = am > 0.f ? 127.f / am : 0.f;
      int gn = row0 + rloc;
      if (lr == 0 && gn < N) scale[invperm[gn]] = am * (1.f / 127.f);
      #pragma unroll
      for (int ct = 0; ct < 8; ++ct) {
        int q = __float2int_rn(o[ct] * inv);
        q8[rloc * DF + ct * 16 + lr] = (uint8_t)(q & 0xff);
      }
    }
  }
  __syncthreads();

  // store: rows scattered via invperm, 128B contiguous per row (full-line)
  #pragma unroll
  for (int it = 0; it < 8; ++it) {
    int chunk = it * 256 + t;
    int rloc = chunk >> 4;
    int gn = row0 + rloc;
    if (gn < N) {
      int gnOut = invperm[gn];
      uint2 v = *(const uint2*)(q8 + chunk * 8);
      *(uint2*)(hl + (size_t)gnOut * DF + (chunk & 15) * 8) = v;
    }
  }
}

// ---------------- layers 1..4 GEMM: hl(int8+scale) = accP @ W^T + b ----------------
__global__ __launch_bounds__(256) void k_gemmb(
    const ushort* __restrict__ in,
    const ushort* __restrict__ Wb, const float* __restrict__ bl,
    uint8_t* __restrict__ hl, float* __restrict__ scale, int N)
{
  __shared__ uint4 lA[128 * 16];
  __shared__ uint4 lW[128 * 16];
  const int t = threadIdx.x;
  const int row0 = blockIdx.x * 128;
  const int wv = t >> 6;
  const int l  = t & 63;

  #pragma unroll
  for (int it = 0; it < 8; ++it) {
    int ubase = (it * 4 + wv) * 64;
    int lin = ubase + l;
    int r = lin >> 4, u = lin & 15;
    gload16((const void*)((const uint4*)Wb + (r << 4) + (u ^ (r & 7))), (void*)(lW + ubase));
  }
  #pragma unroll
  for (int it = 0; it < 8; ++it) {
    int ubase = (it * 4 + wv) * 64;
    int lin = ubase + l;
    int r = lin >> 4, u = lin & 15;
    int gn = row0 + r;
    int gnc = gn < N ? gn : N - 1;
    gload16((const void*)((const uint4*)in + (size_t)gnc * 16 + (u ^ (r & 7))),
            (void*)(lA + ubase));
  }
  __syncthreads();

  const int lr = l & 15;
  const int lk = l >> 4;

  f32x4 acc[2][8];
  #pragma unroll
  for (int rt = 0; rt < 2; ++rt)
    #pragma unroll
    for (int ct = 0; ct < 8; ++ct) acc[rt][ct] = (f32x4){0.f, 0.f, 0.f, 0.f};

  #pragma unroll
  for (int ks = 0; ks < 4; ++ks) {
    const int kofs = ks * 4 + lk;
    bf16x8 af[2], wf[8];
    #pragma unroll
    for (int rt = 0; rt < 2; ++rt) {
      int r = wv * 32 + rt * 16 + lr;
      af[rt] = *reinterpret_cast<const bf16x8*>(&lA[(r << 4) | (kofs ^ (r & 7))]);
    }
    #pragma unroll
    for (int ct = 0; ct < 8; ++ct) {
      int r = ct * 16 + lr;
      wf[ct] = *reinterpret_cast<const bf16x8*>(&lW[(r << 4) | (kofs ^ (r & 7))]);
    }
    #pragma unroll
    for (int rt = 0; rt < 2; ++rt)
      #pragma unroll
      for (int ct = 0; ct < 8; ++ct)
        acc[rt][ct] = __builtin_amdgcn_mfma_f32_16x16x32_bf16(af[rt], wf[ct], acc[rt][ct], 0, 0, 0);
  }

  float bb[8];
  #pragma unroll
  for (int ct = 0; ct < 8; ++ct) bb[ct] = bl[ct * 16 + lr];

  __syncthreads();
  uint8_t* q8 = (uint8_t*)lA;

  #pragma unroll
  for (int rt = 0; rt < 2; ++rt) {
    #pragma unroll
    for (int rg = 0; rg < 4; ++rg) {
      int rloc = wv * 32 + rt * 16 + lk * 4 + rg;
      float o[8];
      float am = 0.f;
      #pragma unroll
      for (int ct = 0; ct < 8; ++ct) {
        o[ct] = acc[rt][ct][rg] + bb[ct];
        am = fmaxf(am, fabsf(o[ct]));
      }
      am = fmaxf(am, __shfl_xor(am, 1));
      am = fmaxf(am, __shfl_xor(am, 2));
      am = fmaxf(am, __shfl_xor(am, 4));
      am = fmaxf(am, __shfl_xor(am, 8));
      float inv = am > 0.f ? 127.f / am : 0.f;
      int gn = row0 + rloc;
      if (lr == 0 && gn < N) scale[gn] = am * (1.f / 127.f);
      #pragma unroll
      for (int ct = 0; ct < 8; ++ct) {
        int q = __float2int_rn(o[ct] * inv);
        q8[rloc * DF + ct * 16 + lr] = (uint8_t)(q & 0xff);
      }
    }
  }
  __syncthreads();

  #pragma unroll
  for (int it = 0; it < 8; ++it) {
    int chunk = it * 256 + t;
    int rloc = chunk >> 4;
    int gn = row0 + rloc;
    if (gn < N) {
      uint2 v = *(const uint2*)(q8 + chunk * 8);
      *(uint2*)(hl + (size_t)gn * DF + (chunk & 15) * 8) = v;
    }
  }
}

// ---------------- segmented gather-reduce (permuted space, int8 hl) ----------------
// 4 dest rows per wave (degree-uniform), 16 lanes/row, 8 feats/lane. (R8 form.)
template <typename AT, bool LAST>
__global__ __launch_bounds__(256) void k_gather(
    const int* __restrict__ startP, const int* __restrict__ degP,
    const float* __restrict__ dinvP,
    const int2* __restrict__ pairS,
    const uint32_t* __restrict__ epS,
    const uint2* __restrict__ hl2, const float* __restrict__ scaleArr,
    const float* __restrict__ rootl, const float* __restrict__ sl,
    const float* __restrict__ tl, const int* __restrict__ perm,
    AT* __restrict__ acc, int N)
{
  int gw = (blockIdx.x * blockDim.x + threadIdx.x) >> 6;
  int lane = threadIdx.x & 63;
  int s16 = lane & 15;
  int i = gw * 4 + (lane >> 4);
  if (i >= N) return;
  int base = startP[i], n = degP[i];
  float di = dinvP[i];
  float invdeg = di * di;
  const uint32_t sh = (s16 & 1) * 16;
  const int dw = s16 >> 1;

  float a[8];
  #pragma unroll
  for (int j = 0; j < 8; ++j) a[j] = 0.f;

  for (int c0 = 0; c0 < n; c0 += 16) {
    int m = min(16, n - c0);
    int2 pv = (s16 < m) ? pairS[base + c0 + s16] : make_int2(0, 0);
    #pragma unroll 4
    for (int k = 0; k < m; ++k) {
      int src = __shfl(pv.x, k, 16);
      float nr = __int_as_float(__shfl(pv.y, k, 16));
      uint32_t pw = epS[(size_t)(base + c0 + k) * 8 + dw];
      uint2 hw = hl2[(size_t)src * 16 + s16];
      float sc = scaleArr[src];
      a[0] += nr * fmaxf(fmaf(i8f(hw.x, 0),  sc, (float)((pw >> (sh + 0))  & 3u)), 0.f);
      a[1] += nr * fmaxf(fmaf(i8f(hw.x, 8),  sc, (float)((pw >> (sh + 2))  & 3u)), 0.f);
      a[2] += nr * fmaxf(fmaf(i8f(hw.x, 16), sc, (float)((pw >> (sh + 4))  & 3u)), 0.f);
      a[3] += nr * fmaxf(fmaf(i8f(hw.x, 24), sc, (float)((pw >> (sh + 6))  & 3u)), 0.f);
      a[4] += nr * fmaxf(fmaf(i8f(hw.y, 0),  sc, (float)((pw >> (sh + 8))  & 3u)), 0.f);
      a[5] += nr * fmaxf(fmaf(i8f(hw.y, 8),  sc, (float)((pw >> (sh + 10)) & 3u)), 0.f);
      a[6] += nr * fmaxf(fmaf(i8f(hw.y, 16), sc, (float)((pw >> (sh + 12)) & 3u)), 0.f);
      a[7] += nr * fmaxf(fmaf(i8f(hw.y, 24), sc, (float)((pw >> (sh + 14)) & 3u)), 0.f);
    }
  }

  uint2 hwS = hl2[(size_t)i * 16 + s16];
  float scS = scaleArr[i];
  float hs[8];
  hs[0] = i8f(hwS.x, 0)  * scS; hs[1] = i8f(hwS.x, 8)  * scS;
  hs[2] = i8f(hwS.x, 16) * scS; hs[3] = i8f(hwS.x, 24) * scS;
  hs[4] = i8f(hwS.y, 0)  * scS; hs[5] = i8f(hwS.y, 8)  * scS;
  hs[6] = i8f(hwS.y, 16) * scS; hs[7] = i8f(hwS.y, 24) * scS;

  float rr[8], ss[8], tt[8];
  ((float4*)rr)[0] = ((const float4*)rootl)[s16 * 2]; ((float4*)rr)[1] = ((const float4*)rootl)[s16 * 2 + 1];
  ((float4*)ss)[0] = ((const float4*)sl)[s16 * 2];    ((float4*)ss)[1] = ((const float4*)sl)[s16 * 2 + 1];
  ((float4*)tt)[0] = ((const float4*)tl)[s16 * 2];    ((float4*)tt)[1] = ((const float4*)tl)[s16 * 2 + 1];

  float o[8];
  #pragma unroll
  for (int j = 0; j < 8; ++j) {
    float self = fmaxf(hs[j] + rr[j], 0.f) * invdeg;
    o[j] = ss[j] * (self + a[j]) + tt[j];
  }

  if constexpr (!LAST) {
    #pragma unroll
    for (int j = 0; j < 8; ++j) o[j] = fmaxf(o[j], 0.f);
    uint4 p;
    p.x = pk2(o[0], o[1]); p.y = pk2(o[2], o[3]);
    p.z = pk2(o[4], o[5]); p.w = pk2(o[6], o[7]);
    ((uint4*)acc)[(size_t)i * 16 + s16] = p;
  } else {
    int nd = perm[i];
    float4* ap = (float4*)acc + (size_t)nd * 32 + s16 * 2;
    ap[0] = make_float4(o[0], o[1], o[2], o[3]);
    ap[1] = make_float4(o[4], o[5], o[6], o[7]);
  }
}

// ---------------- launch ----------------
extern "C" void kernel_launch(void* const* d_in, const int* in_sizes, int n_in,
                              void* d_out, int out_size, void* d_ws, size_t ws_size,
                              hipStream_t stream) {
  const float* x     = (const float*)d_in[0];
  const int*   ei    = (const int*)d_in[1];
  const int*   ea    = (const int*)d_in[2];
  const float* W     = (const float*)d_in[3];
  const float* b     = (const float*)d_in[4];
  const float* root  = (const float*)d_in[5];
  const float* gamma = (const float*)d_in[6];
  const float* beta  = (const float*)d_in[7];
  const float* mean  = (const float*)d_in[8];
  const float* var   = (const float*)d_in[9];

  const int N = in_sizes[0] / DF;
  const int E = in_sizes[1] / 2;
  const int* row = ei;
  const int* col = ei + E;

  char* ws = (char*)d_ws;
  size_t off = 0;
  auto alloc = [&](size_t bytes) -> void* {
    void* p = ws + off;
    off = (off + bytes + 255) & ~(size_t)255;
    return p;
  };
  int*      degi    = (int*)alloc((size_t)N * 4);
  int*      indeg   = (int*)alloc((size_t)N * 4);
  int*      hist    = (int*)alloc((size_t)NB * 4);
  int*      binCur  = (int*)alloc((size_t)NB * 4);
  size_t    zspan   = (size_t)((char*)ws + off - (char*)degi);
  float*    dinv    = (float*)alloc((size_t)N * 4);
  int*      nodeSt  = (int*)alloc((size_t)NB * 4);
  int*      edgeSt  = (int*)alloc((size_t)NB * 4);
  int*      perm    = (int*)alloc((size_t)N * 4);
  int*      invperm = (int*)alloc((size_t)N * 4);
  int*      startP  = (int*)alloc((size_t)N * 4);
  int*      cursorP = (int*)alloc((size_t)N * 4);
  int*      degP    = (int*)alloc((size_t)N * 4);
  float*    dinvP   = (float*)alloc((size_t)N * 4);
  int2*     pairS   = (int2*)alloc((size_t)E * 8);
  uint32_t* epS     = (uint32_t*)alloc((size_t)E * 8 * 4);
  float*    sbuf    = (float*)alloc((size_t)NL * DF * 4);
  float*    tbuf    = (float*)alloc((size_t)NL * DF * 4);
  ushort*   Wb      = (ushort*)alloc((size_t)NL * DF * DF * 2);
  uint8_t*  hl      = (uint8_t*)alloc((size_t)N * DF);
  float*    scaleA  = (float*)alloc((size_t)N * 4);
  ushort*   accP    = (ushort*)alloc((size_t)N * DF * 2);

  hipMemsetAsync(degi, 0, zspan, stream);

  k_deg2<<<((E + 1) / 2 + 255) / 256, 256, 0, stream>>>(row, col, degi, indeg, E);
  k_dinvhist<<<(N + 255) / 256, 256, 0, stream>>>(degi, indeg, dinv, hist, N);
  k_scan<<<1, NB, 0, stream>>>(hist, nodeSt, edgeSt);
  k_assign<<<(N + 255) / 256, 256, 0, stream>>>(indeg, dinv, nodeSt, edgeSt, binCur,
                                                perm, invperm, startP, cursorP,
                                                degP, dinvP, N);
  k_fillpack<<<(E * 8 + 255) / 256, 256, 0, stream>>>(row, col, dinv, invperm, cursorP,
                                                      pairS, ea, epS, E);
  k_params<<<(NL * DF * DF + 255) / 256, 256, 0, stream>>>(
      gamma, beta, mean, var, sbuf, tbuf, W, Wb, NL * DF, NL * DF * DF);

  float* outp = (float*)d_out;
  const int gemmGrid = (N + 127) / 128;
  const int gathGrid = (N + 3) / 4;   // 1 wave per 4 nodes; 256-thread blocks
  const int gathBlocks = (gathGrid * 64 + 255) / 256;

  // layer 0: sequential x read, scatter hl via invperm
  k_gemm0<<<gemmGrid, 256, 0, stream>>>(x, invperm, Wb, b, hl, scaleA, N);
  k_gather<ushort, false><<<gathBlocks, 256, 0, stream>>>(
      startP, degP, dinvP, pairS, epS, (const uint2*)hl, scaleA,
      root, sbuf, tbuf, perm, accP, N);

  for (int l = 1; l < NL - 1; ++l) {
    k_gemmb<<<gemmGrid, 256, 0, stream>>>(
        accP, Wb + (size_t)l * DF * DF, b + (size_t)l * DF, hl, scaleA, N);
    k_gather<ushort, false><<<gathBlocks, 256, 0, stream>>>(
        startP, degP, dinvP, pairS, epS, (const uint2*)hl, scaleA,
        root + (size_t)l * DF, sbuf + (size_t)l * DF, tbuf + (size_t)l * DF,
        perm, accP, N);
  }

  {
    const int l = NL - 1;
    k_gemmb<<<gemmGrid, 256, 0, stream>>>(
        accP, Wb + (size_t)l * DF * DF, b + (size_t)l * DF, hl, scaleA, N);
    k_gather<float, true><<<gathBlocks, 256, 0, stream>>>(
        startP, degP, dinvP, pairS, epS, (const uint2*)hl, scaleA,
        root + (size_t)l * DF, sbuf + (size_t)l * DF, tbuf + (size_t)l * DF,
        perm, outp, N);
  }
}